// Round 7
// baseline (159.772 us; speedup 1.0000x reference)
//
#include <hip/hip_runtime.h>

#define M1 81
#define MSZ 80
#define NEL (M1 * M1)          // 6561
#define NTW ((NEL + 31) / 32)  // 206 words of target bits
#define NACC 12
#define BIGKC 1.0e30f
#define REDP 517               // padded stride for reduce scratch (bank spread)

// accumulator indices:
// 0 target_num, 1 n_pre, 2 n_next, 3 n_union,
// 4 s_pre, 5 s_next, 6 s_all, 7 s_sim,
// 8 s_acc_pre, 9 s_acc_next, 10 n_mpre, 11 n_mnext

__global__ __launch_bounds__(512, 8) void sst_main(
    const float* __restrict__ input,
    const int* __restrict__ target,
    const int* __restrict__ mask0,
    const int* __restrict__ mask1,
    float* __restrict__ out_idx,   // d_out + 7, [slices*80] floats
    float* __restrict__ part,      // SoA: part[k*nparts + block]
    int slices,
    int nparts)
{
    __shared__ __align__(16) float s_x[NEL];  // e-values; reduce scratch at end
    __shared__ unsigned s_tb[NTW];       // target bits, row-major
    __shared__ float s_m0[2][M1], s_m1[2][M1];
    __shared__ float s_kc[M1];           // log(csum) (1e30 sentinel @80)
    __shared__ float s_invc[M1];         // 1/csum (0 sentinel @80)
    __shared__ unsigned char s_ci[2][M1];// per-column argmax row
    __shared__ int s_ct[2][MSZ];         // per-column first target row
    __shared__ unsigned s_m1w[2][4];     // m1 bitmask per slice parity

    const int tid   = threadIdx.x;
    const int lane  = tid & 63;
    const int slice0 = blockIdx.x * 2;
    const int slice1 = slice0 + 1;
    const bool s2 = (slice1 < slices);

    // 4-thread lane-aligned groups: g = column (sweep A) / row (sweep C).
    const bool act = (tid < 4 * M1);          // 324 threads
    const int g   = tid >> 2;
    const int j4  = tid & 3;
    const int c0j = (j4 == 0) ? 0 : (1 + 20 * j4);   // {0,21,41,61}
    const int lm1 = (j4 == 0) ? 0x1FFFFF : 0xFFFFF;  // 21-/20-bit masks

    if (tid < M1) s_m0[0][tid] = (float)mask0[slice0 * M1 + tid];
    else if (tid >= 128 && tid < 128 + M1) s_m1[0][tid - 128] = (float)mask1[slice0 * M1 + (tid - 128)];
    if (tid >= 256 && tid < 256 + MSZ) s_ct[0][tid - 256] = 0x7fffffff;
    else if (tid >= 352 && tid < 352 + MSZ) s_ct[1][tid - 352] = 0x7fffffff;

    float a[NACC];
#pragma unroll
    for (int k = 0; k < NACC; ++k) a[k] = 0.0f;

    float v[21];      // input values (reloaded per slice; dead between uses)
    int tpre[13];     // target values (reloaded per slice)

    // ---- helpers (all static-indexed; inlined) ----
    auto loadV = [&](int sl) {
        if (act) {
            const float* gp = input + (size_t)sl * NEL + (size_t)c0j * M1 + g;
#pragma unroll
            for (int i = 0; i < 20; ++i) v[i] = gp[i * M1];
            v[20] = gp[((j4 == 0) ? 20 : 0) * M1];   // 21st row only for j4==0
        }
    };
    auto loadT = [&](int sl) {
        const size_t tb_ = (size_t)sl * NEL;
#pragma unroll
        for (int k = 0; k < 13; ++k) {
            const int i = tid + (k << 9);
            tpre[k] = (i < NEL) ? target[tb_ + i] : 0;
        }
    };
    auto bitpack = [&]() {
#pragma unroll
        for (int k = 0; k < 13; ++k) {
            const int i = tid + (k << 9);
            if (i < NEL) {
                const unsigned long long m = __ballot(tpre[k] != 0);
                if (lane == 0) {
                    a[0] += (float)__popcll(m);
                    const int w2 = (i >> 5) & ~1;
                    s_tb[w2] = (unsigned)m;
                    if (w2 + 1 < NTW) s_tb[w2 + 1] = (unsigned)(m >> 32);
                }
            }
        }
    };
    auto sweepA = [&](int p) {
        if (act) {
            const int c = g;
            const float m1c = s_m1[p][c];
            float cs = 0.0f, bv = -1.0f;
            int bi = c0j;
            int idx = c0j * M1 + c;
#pragma unroll
            for (int i = 0; i < 20; ++i, idx += M1) {
                const int r = c0j + i;
                const float z = m1c * s_m0[p][r] * v[i];
                const float e = __expf(z);
                s_x[idx] = e;                     // same-thread region: race-free
                cs += e;
                if (e > bv) { bv = e; bi = r; }   // first-max (ascending r)
            }
            if (j4 == 0) {                        // row 20
                const float z = m1c * s_m0[p][20] * v[20];
                const float e = __expf(z);
                s_x[20 * M1 + c] = e;
                cs += e;
                if (e > bv) { bv = e; bi = 20; }
            }
#pragma unroll
            for (int m = 1; m <= 2; m <<= 1) {    // left-pref tournament
                const float pcs = __shfl_xor(cs, m);
                const float pbv = __shfl_xor(bv, m);
                const int   pbi = __shfl_xor(bi, m);
                cs += pcs;
                const bool take = (lane & m) ? (pbv >= bv) : (pbv > bv);
                if (take) { bv = pbv; bi = pbi; }
            }
            if (j4 == 0) {
                s_kc[c]   = (c == MSZ) ? BIGKC : __logf(cs);
                s_invc[c] = (c == MSZ) ? 0.0f  : 1.0f / cs;
                s_ci[p][c] = (unsigned char)bi;
            }
        }
    };
    auto sweepC = [&](int p, int sl) {
        const int r = g;
        const int rb = r * M1;
        const int bp = rb + c0j;
        const unsigned long long tw64 =
            ((unsigned long long)s_tb[(bp >> 5) + 1] << 32) | s_tb[bp >> 5];
        const int mp0 = c0j >> 5;
        const unsigned long long mw64 =
            ((unsigned long long)s_m1w[p][mp0 + 1] << 32) | s_m1w[p][mp0];
        unsigned wb = (unsigned)(tw64 >> (bp & 31)) & (unsigned)(mw64 >> (c0j & 31)) & (unsigned)lm1;

        if (r < MSZ) {
            const float m0f = s_m0[p][r];
            if (m0f == 0.0f) wb = 0u;
            float rs = 0.0f;
#pragma unroll
            for (int i = 0; i < 20; ++i) rs += s_x[rb + c0j + i];
            if (j4 == 0) rs += s_x[rb + 20];
            rs += __shfl_xor(rs, 1);
            rs += __shfl_xor(rs, 2);
            const float lr = __logf(rs), invr = 1.0f / rs;

            const unsigned w3 = (j4 == 3) ? (wb & 0x7FFFFu) : wb;  // drop c=80
            a[1] += (float)__popc(wb);
            a[2] += (float)__popc(w3);
            a[3] += (float)__popc(w3);
            int ti = wb ? (c0j + __ffs(wb) - 1) : 127;

            float bv = -1.0f; int bi = c0j;
#pragma unroll
            for (int i = 0; i < 20; ++i) {
                const int c = c0j + i;
                const float val = s_x[rb + c] * fmaxf(invr, s_invc[c]);
                if (val > bv) { bv = val; bi = c; }   // strict >: first-max
            }
            if (j4 == 0) {
                const float val = s_x[rb + 20] * fmaxf(invr, s_invc[20]);
                if (val > bv) { bv = val; bi = 20; }
            }
            unsigned wl = wb;
            while (wl) {
                const int b = __ffs(wl) - 1; wl &= wl - 1u;
                const int c = c0j + b;
                const float e = s_x[rb + c];
                const float z = __logf(e);
                a[4] += lr - z;
                a[6] += fminf(lr, s_kc[c]) - z;
                if (c != MSZ) {
                    a[5] += s_kc[c] - z;
                    a[7] = fmaf(e, fabsf(s_invc[c] - invr), a[7]);
                    atomicMin(&s_ct[p][c], r);
                }
            }
#pragma unroll
            for (int m = 1; m <= 2; m <<= 1) {
                const float pbv = __shfl_xor(bv, m);
                const int   pbi = __shfl_xor(bi, m);
                const int   pti = __shfl_xor(ti, m);
                const bool take = (lane & m) ? (pbv >= bv) : (pbv > bv);
                if (take) { bv = pbv; bi = pbi; }
                ti = min(ti, pti);
            }
            if (j4 == 0) {
                if (ti == 127) ti = 0;
                out_idx[(size_t)sl * MSZ + r] = (float)bi;
                a[8]  += (bi == ti) ? m0f : 0.0f;
                a[10] += m0f;
            }
        } else {
            // row 80: only n_next / s_next / ct terms survive
            if (s_m0[p][MSZ] == 0.0f) wb = 0u;
            if (j4 == 3) wb &= 0x7FFFFu;
            a[2] += (float)__popc(wb);
            while (wb) {
                const int b = __ffs(wb) - 1; wb &= wb - 1u;
                const int c = c0j + b;
                a[5] += s_kc[c] - __logf(s_x[rb + c]);
                atomicMin(&s_ct[p][c], MSZ);
            }
        }
    };
    auto accN = [&](int p) {
        if (tid < MSZ) {
            const int ctv = s_ct[p][tid];
            const int ti = (ctv == 0x7fffffff) ? 0 : ctv;
            const int bi = (int)s_ci[p][tid];
            const float m1c = s_m1[p][tid];
            a[9]  += (bi == ti) ? m1c : 0.0f;
            a[11] += m1c;
        }
    };

    __syncthreads();   // B1 (masks0 + ct inits)

    // ---- slice 0 ----
    loadV(slice0);                 // issued first: A0 waits only on these
    loadT(slice0);                 // consumed after A0 -> hides under exp
    if ((tid >> 6) == 0) {         // m1w[0] windows
        const unsigned long long m = __ballot(s_m1[0][lane] != 0.0f);
        if (lane == 0) { s_m1w[0][0] = (unsigned)m; s_m1w[0][1] = (unsigned)(m >> 32); }
    } else if ((tid >> 6) == 1) {
        float vv = 0.0f;
        if (lane < 17) vv = s_m1[0][64 + lane];
        const unsigned long long m = __ballot(vv != 0.0f);
        if (lane == 0) { s_m1w[0][2] = (unsigned)m; s_m1w[0][3] = 0u; }
    }
    sweepA(0);
    bitpack();
    __syncthreads();   // B2

    if (s2) loadV(slice1);         // slice1 x-loads fly under ALL of sweep C0
    if (act) {
        sweepC(0, slice0);
    } else if (tid >= 384 && s2) { // waves 6-7 (idle in C): slice1 masks + m1w
        const int u = tid - 384;
        if (u < M1) s_m0[1][u] = (float)mask0[slice1 * M1 + u];
        float m1v = 0.0f;
        if (u < M1) { m1v = (float)mask1[slice1 * M1 + u]; s_m1[1][u] = m1v; }
        const unsigned long long mm = __ballot(m1v != 0.0f);
        if (u == 0)       { s_m1w[1][0] = (unsigned)mm; s_m1w[1][1] = (unsigned)(mm >> 32); }
        else if (u == 64) { s_m1w[1][2] = (unsigned)mm; s_m1w[1][3] = 0u; }
    }
    __syncthreads();   // B4 (C0 done; slice1 masks in)

    accN(0);
    if (s2) {
        loadT(slice1);             // hides under A1 exp
        sweepA(1);                 // v ready since B2-epoch
        bitpack();
    }
    __syncthreads();   // B2'
    if (s2 && act) sweepC(1, slice1);
    __syncthreads();   // B4'
    if (s2) accN(1);

    // ---- block reduce (once, both slices accumulated): LDS transpose ----
    float* red = s_x;              // s_x dead
#pragma unroll
    for (int k = 0; k < NACC; ++k) red[k * REDP + tid] = a[k];
    __syncthreads();   // B5
    if (tid < 96) {
        const int k = tid >> 3, u = tid & 7;
        const int b0 = k * REDP + u * 64;
        const int i0 = u * 4;                 // bank stagger across u
        float s = 0.0f;
        for (int i = 0; i < 64; ++i) s += red[b0 + ((i0 + i) & 63)];
        s += __shfl_xor(s, 1);
        s += __shfl_xor(s, 2);
        s += __shfl_xor(s, 4);
        if (u == 0) part[(size_t)k * nparts + blockIdx.x] = s;
    }
}

__global__ __launch_bounds__(256) void sst_final(
    const float* __restrict__ part, int n, float* __restrict__ out)
{
    __shared__ double s_part[4][NACC];
    const int tid = threadIdx.x;
    double l[NACC];
#pragma unroll
    for (int k = 0; k < NACC; ++k) l[k] = 0.0;
    for (int s = tid; s < n; s += 256) {
#pragma unroll
        for (int k = 0; k < NACC; ++k) l[k] += (double)part[(size_t)k * n + s];
    }
#pragma unroll
    for (int k = 0; k < NACC; ++k) {
        double v = l[k];
        for (int off = 32; off > 0; off >>= 1) v += __shfl_down(v, off);
        if ((tid & 63) == 0) s_part[tid >> 6][k] = v;
    }
    __syncthreads();
    if (tid == 0) {
        double g[NACC];
#pragma unroll
        for (int k = 0; k < NACC; ++k)
            g[k] = s_part[0][k] + s_part[1][k] + s_part[2][k] + s_part[3][k];
        const double tnum = g[0], npre = g[1], nnext = g[2], nunion = g[3];
        const double spre = g[4], snext = g[5], sall = g[6], ssim = g[7];
        const double accp = g[8], accn = g[9], nmp = g[10], nmn = g[11];
        const double loss_pre  = (npre > 0.0) ? spre / npre : spre;
        const double loss_next = (nnext > 0.0) ? snext / nnext : snext;
        const double loss      = (npre > 0.0 && nnext > 0.0) ? sall / npre : sall;
        const double loss_sim  = (nunion > 0.0) ? ssim / tnum : ssim;
        const double total = (loss_pre + loss_next + loss + loss_sim) * 0.25;
        const double ap = (nmp > 0.0) ? accp / nmp : accp + 1.0;
        const double an = (nmn > 0.0) ? accn / nmn : accn + 1.0;
        out[0] = (float)loss_pre;
        out[1] = (float)loss_next;
        out[2] = (float)loss_sim;
        out[3] = (float)total;
        out[4] = (float)ap;
        out[5] = (float)an;
        out[6] = (float)((ap + an) * 0.5);
    }
}

extern "C" void kernel_launch(void* const* d_in, const int* in_sizes, int n_in,
                              void* d_out, int out_size, void* d_ws, size_t ws_size,
                              hipStream_t stream) {
    const float* input  = (const float*)d_in[0];
    const int*   target = (const int*)d_in[1];
    const int*   mask0  = (const int*)d_in[2];
    const int*   mask1  = (const int*)d_in[3];
    float* out = (float*)d_out;
    float* part = (float*)d_ws;   // NACC * nblocks floats, SoA

    const int slices  = in_sizes[0] / NEL;   // B*C = 2048
    const int nblocks = (slices + 1) / 2;    // 2 slices per block

    sst_main<<<nblocks, 512, 0, stream>>>(input, target, mask0, mask1,
                                          out + 7, part, slices, nblocks);
    sst_final<<<1, 256, 0, stream>>>(part, nblocks, out);
}

// Round 8
// 149.583 us; speedup vs baseline: 1.0681x; 1.0681x over previous
//
#include <hip/hip_runtime.h>

#define M1 81
#define MSZ 80
#define NEL (M1 * M1)          // 6561
#define NTW ((NEL + 31) / 32)  // 206 words of target bits
#define NACC 12
#define BIGKC 1.0e30f
#define REDP 517               // padded stride for reduce scratch (bank spread)

// accumulator indices:
// 0 target_num, 1 n_pre, 2 n_next, 3 n_union,
// 4 s_pre, 5 s_next, 6 s_all, 7 s_sim,
// 8 s_acc_pre, 9 s_acc_next, 10 n_mpre, 11 n_mnext

__global__ __launch_bounds__(512, 8) void sst_main(
    const float* __restrict__ input,
    const int* __restrict__ target,
    const int* __restrict__ mask0,
    const int* __restrict__ mask1,
    float* __restrict__ out_idx,   // d_out + 7, [slices*80] floats
    float* __restrict__ part,      // SoA: part[k*slices + slice]
    int slices)
{
    __shared__ __align__(16) float s_x[NEL];  // e-values; reduce scratch at end
    __shared__ unsigned s_tb[NTW];      // target bits, row-major
    __shared__ float s_m0[M1], s_m1[M1];
    __shared__ float s_kc[M1];          // log(csum) (1e30 sentinel @80)
    __shared__ float s_invc[M1];        // 1/csum (0 sentinel @80 for argmax)
    __shared__ unsigned char s_ci[M1];  // per-column argmax row
    __shared__ int s_ct[MSZ];           // per-column first target row (atomicMin)
    __shared__ unsigned s_m1w[4];       // m1 bitmask (bit c = mask1[c] != 0)

    const int tid   = threadIdx.x;
    const int lane  = tid & 63;
    const int slice = blockIdx.x;
    const size_t base = (size_t)slice * NEL;

    // 4-thread groups (lane-aligned): group g = tid>>2 is a column in sweep A,
    // a row in sweep C; j4 = tid&3 selects the 21/20/20/20 line split.
    const bool act = (tid < 4 * M1);          // 324 threads
    const int g   = tid >> 2;
    const int j4  = tid & 3;
    const int c0j = (j4 == 0) ? 0 : (1 + 20 * j4);   // {0,21,41,61}
    const int lm1 = (j4 == 0) ? 0x1FFFFF : 0xFFFFF;  // 21- / 20-bit masks

    if (tid < M1) s_m0[tid] = (float)mask0[slice * M1 + tid];
    else if (tid >= 128 && tid < 128 + M1) s_m1[tid - 128] = (float)mask1[slice * M1 + (tid - 128)];
    if (tid >= 256 && tid < 256 + MSZ) s_ct[tid - 256] = 0x7fffffff;

    float a[NACC];
#pragma unroll
    for (int k = 0; k < NACC; ++k) a[k] = 0.0f;

    __syncthreads();   // B1 (masks + s_ct)

    // ---- sweep A issue: column-strided loads into regs (issued first, so
    //      A's compute waits only on these; FIFO vmcnt) ----
    float v[21];
    if (act) {
        const float* gp = input + base + (size_t)c0j * M1 + g;
#pragma unroll
        for (int i = 0; i < 20; ++i) v[i] = gp[i * M1];
        // 21st element only for j4==0 (rows 0..20); clamp addr for others
        v[20] = gp[((j4 == 0) ? 20 : 0) * M1];
    }

    // target prefetch: consumed after sweep A -> latency hides under exp
    int tpre[13];
#pragma unroll
    for (int k = 0; k < 13; ++k) {
        const int i = tid + (k << 9);
        tpre[k] = (i < NEL) ? target[base + i] : 0;
    }

    // m1 bit windows (consumed in sweep C)
    if ((tid >> 6) == 0) {
        const unsigned long long m = __ballot(s_m1[lane] != 0.0f);
        if (lane == 0) { s_m1w[0] = (unsigned)m; s_m1w[1] = (unsigned)(m >> 32); }
    } else if ((tid >> 6) == 1) {
        float vv = 0.0f;
        if (lane < 17) vv = s_m1[64 + lane];
        const unsigned long long m = __ballot(vv != 0.0f);
        if (lane == 0) { s_m1w[2] = (unsigned)m; s_m1w[3] = 0u; }
    }

    // ---- sweep A compute: 4 threads per column; butterfly merges the
    //      column sum + first-max argmax in-register ----
    if (act) {
        const int c = g;
        const float m1c = s_m1[c];
        float cs = 0.0f, bv = -1.0f;
        int bi = c0j;
        int idx = c0j * M1 + c;
#pragma unroll
        for (int i = 0; i < 20; ++i, idx += M1) {
            const int r = c0j + i;
            const float z = m1c * s_m0[r] * v[i];
            const float e = __expf(z);
            s_x[idx] = e;                     // same-thread region: race-free
            cs += e;
            if (e > bv) { bv = e; bi = r; }   // first-max (ascending r)
        }
        if (j4 == 0) {                        // row 20 (scanned last: ascending)
            const float z = m1c * s_m0[20] * v[20];
            const float e = __expf(z);
            s_x[20 * M1 + c] = e;
            cs += e;
            if (e > bv) { bv = e; bi = 20; }
        }
        // butterfly over the aligned 4-lane group; left-preferring tournament
        // reproduces first-max over ascending r exactly.
#pragma unroll
        for (int m = 1; m <= 2; m <<= 1) {
            const float pcs = __shfl_xor(cs, m);
            const float pbv = __shfl_xor(bv, m);
            const int   pbi = __shfl_xor(bi, m);
            cs += pcs;
            const bool take = (lane & m) ? (pbv >= bv) : (pbv > bv);
            if (take) { bv = pbv; bi = pbi; }
        }
        if (j4 == 0) {
            s_kc[c]   = (c == MSZ) ? BIGKC : __logf(cs);
            s_invc[c] = (c == MSZ) ? 0.0f  : 1.0f / cs;
            s_ci[c]   = (unsigned char)bi;
        }
    }

    // ---- target bit-pack (prefetched regs -> ballot -> s_tb) + target_num ----
#pragma unroll
    for (int k = 0; k < 13; ++k) {
        const int i = tid + (k << 9);
        if (i < NEL) {
            const unsigned long long m = __ballot(tpre[k] != 0);
            if (lane == 0) {
                a[0] += (float)__popcll(m);
                const int w2 = (i >> 5) & ~1;
                s_tb[w2] = (unsigned)m;
                if (w2 + 1 < NTW) s_tb[w2 + 1] = (unsigned)(m >> 32);
            }
        }
    }
    __syncthreads();   // B2

    // ---- sweep C: 4 threads per row; SINGLE fused pass computes row sum +
    //      dual argmax (E-side: raw e, monotone proxy for e*invr; T-side:
    //      e*invc). After the sum butterfly, combine:
    //      max_c e*max(invr,invc) = max(bvE*invr, bvT); first-index on ties.
    if (act) {
        const int r = g;
        const int rb = r * M1;
        const int bp = rb + c0j;
        const unsigned long long tw64 =
            ((unsigned long long)s_tb[(bp >> 5) + 1] << 32) | s_tb[bp >> 5];
        const int mp0 = c0j >> 5;
        const unsigned long long mw64 =
            ((unsigned long long)s_m1w[mp0 + 1] << 32) | s_m1w[mp0];
        unsigned wb = (unsigned)(tw64 >> (bp & 31)) & (unsigned)(mw64 >> (c0j & 31)) & (unsigned)lm1;

        if (r < MSZ) {
            const float m0f = s_m0[r];
            if (m0f == 0.0f) wb = 0u;

            float rs = 0.0f, bvE = -1.0f, bvT = -1.0f;
            int biE = c0j, biT = c0j;
#pragma unroll
            for (int i = 0; i < 20; ++i) {
                const int c = c0j + i;
                const float e = s_x[rb + c];
                rs += e;
                if (e > bvE) { bvE = e; biE = c; }          // first-max raw e
                const float t = e * s_invc[c];
                if (t > bvT) { bvT = t; biT = c; }          // first-max e*invc
            }
            if (j4 == 0) {                                  // c = 20, last
                const float e = s_x[rb + 20];
                rs += e;
                if (e > bvE) { bvE = e; biE = 20; }
                const float t = e * s_invc[20];
                if (t > bvT) { bvT = t; biT = 20; }
            }
            rs += __shfl_xor(rs, 1);
            rs += __shfl_xor(rs, 2);
            const float lr = __logf(rs), invr = 1.0f / rs;

            // local combine (exact: rn(e*max(a,b)) == max(rn(e*a),rn(e*b)))
            const float A = bvE * invr;
            float bv; int bi;
            if (A > bvT)      { bv = A;   bi = biE; }
            else if (bvT > A) { bv = bvT; bi = biT; }
            else              { bv = A;   bi = min(biE, biT); }

            const unsigned w3 = (j4 == 3) ? (wb & 0x7FFFFu) : wb;  // drop c=80
            a[1] += (float)__popc(wb);
            a[2] += (float)__popc(w3);
            a[3] += (float)__popc(w3);
            int ti = wb ? (c0j + __ffs(wb) - 1) : 127;

            // sparse t-terms
            unsigned wl = wb;
            while (wl) {
                const int b = __ffs(wl) - 1; wl &= wl - 1u;
                const int c = c0j + b;
                const float e = s_x[rb + c];
                const float z = __logf(e);
                a[4] += lr - z;
                a[6] += fminf(lr, s_kc[c]) - z;
                if (c != MSZ) {
                    a[5] += s_kc[c] - z;
                    a[7] = fmaf(e, fabsf(s_invc[c] - invr), a[7]);
                    atomicMin(&s_ct[c], r);
                }
            }
            // butterfly merge: argmax (left-pref) + first-target (min)
#pragma unroll
            for (int m = 1; m <= 2; m <<= 1) {
                const float pbv = __shfl_xor(bv, m);
                const int   pbi = __shfl_xor(bi, m);
                const int   pti = __shfl_xor(ti, m);
                const bool take = (lane & m) ? (pbv >= bv) : (pbv > bv);
                if (take) { bv = pbv; bi = pbi; }
                ti = min(ti, pti);
            }
            if (j4 == 0) {
                if (ti == 127) ti = 0;
                out_idx[(size_t)slice * MSZ + r] = (float)bi;
                a[8]  += (bi == ti) ? m0f : 0.0f;
                a[10] += m0f;
            }
        } else {
            // row 80: only n_next / s_next / ct terms survive
            if (s_m0[MSZ] == 0.0f) wb = 0u;
            if (j4 == 3) wb &= 0x7FFFFu;                     // drop c=80
            a[2] += (float)__popc(wb);
            while (wb) {
                const int b = __ffs(wb) - 1; wb &= wb - 1u;
                const int c = c0j + b;
                a[5] += s_kc[c] - __logf(s_x[rb + c]);
                atomicMin(&s_ct[c], MSZ);
            }
        }
    }
    __syncthreads();   // B4 (s_ct/argmax done; s_x reads done)

    if (tid < MSZ) {   // accuracy_next (cols 0..79)
        const int ctv = s_ct[tid];
        const int ti = (ctv == 0x7fffffff) ? 0 : ctv;
        const int bi = (int)s_ci[tid];
        const float m1c = s_m1[tid];
        a[9]  += (bi == ti) ? m1c : 0.0f;
        a[11] += m1c;
    }

    // ---- block reduce: LDS transpose (s_x is dead -> scratch) ----
    float* red = s_x;
#pragma unroll
    for (int k = 0; k < NACC; ++k) red[k * REDP + tid] = a[k];
    __syncthreads();   // B5
    if (tid < 96) {
        const int k = tid >> 3, u = tid & 7;
        const int b0 = k * REDP + u * 64;
        const int i0 = u * 4;                 // bank stagger across u
        float s = 0.0f;
        for (int i = 0; i < 64; ++i) s += red[b0 + ((i0 + i) & 63)];
        s += __shfl_xor(s, 1);
        s += __shfl_xor(s, 2);
        s += __shfl_xor(s, 4);
        if (u == 0) part[(size_t)k * slices + slice] = s;
    }
}

__global__ __launch_bounds__(256) void sst_final(
    const float* __restrict__ part, int slices, float* __restrict__ out)
{
    __shared__ double s_part[4][NACC];
    const int tid = threadIdx.x;
    double l[NACC];
#pragma unroll
    for (int k = 0; k < NACC; ++k) l[k] = 0.0;
    for (int s = tid; s < slices; s += 256) {
#pragma unroll
        for (int k = 0; k < NACC; ++k) l[k] += (double)part[(size_t)k * slices + s];
    }
#pragma unroll
    for (int k = 0; k < NACC; ++k) {
        double v = l[k];
        for (int off = 32; off > 0; off >>= 1) v += __shfl_down(v, off);
        if ((tid & 63) == 0) s_part[tid >> 6][k] = v;
    }
    __syncthreads();
    if (tid == 0) {
        double g[NACC];
#pragma unroll
        for (int k = 0; k < NACC; ++k)
            g[k] = s_part[0][k] + s_part[1][k] + s_part[2][k] + s_part[3][k];
        const double tnum = g[0], npre = g[1], nnext = g[2], nunion = g[3];
        const double spre = g[4], snext = g[5], sall = g[6], ssim = g[7];
        const double accp = g[8], accn = g[9], nmp = g[10], nmn = g[11];
        const double loss_pre  = (npre > 0.0) ? spre / npre : spre;
        const double loss_next = (nnext > 0.0) ? snext / nnext : snext;
        const double loss      = (npre > 0.0 && nnext > 0.0) ? sall / npre : sall;
        const double loss_sim  = (nunion > 0.0) ? ssim / tnum : ssim;
        const double total = (loss_pre + loss_next + loss + loss_sim) * 0.25;
        const double ap = (nmp > 0.0) ? accp / nmp : accp + 1.0;
        const double an = (nmn > 0.0) ? accn / nmn : accn + 1.0;
        out[0] = (float)loss_pre;
        out[1] = (float)loss_next;
        out[2] = (float)loss_sim;
        out[3] = (float)total;
        out[4] = (float)ap;
        out[5] = (float)an;
        out[6] = (float)((ap + an) * 0.5);
    }
}

extern "C" void kernel_launch(void* const* d_in, const int* in_sizes, int n_in,
                              void* d_out, int out_size, void* d_ws, size_t ws_size,
                              hipStream_t stream) {
    const float* input  = (const float*)d_in[0];
    const int*   target = (const int*)d_in[1];
    const int*   mask0  = (const int*)d_in[2];
    const int*   mask1  = (const int*)d_in[3];
    float* out = (float*)d_out;
    float* part = (float*)d_ws;   // NACC * slices floats, SoA

    const int slices = in_sizes[0] / NEL;  // B*C = 2048

    sst_main<<<slices, 512, 0, stream>>>(input, target, mask0, mask1, out + 7, part, slices);
    sst_final<<<1, 256, 0, stream>>>(part, slices, out);
}